// Round 1
// baseline (1604.265 us; speedup 1.0000x reference)
//
#include <hip/hip_runtime.h>
#include <hip/hip_bf16.h>
#include <cstdint>

// Neural ODE: 10 Heun steps of f(y) = tanh(y@W1 + b1)@W2 + b2
// BATCH=8192, D=512, H=2048, dt=0.1
// Strategy: bf16 MFMA GEMMs (m97-style 128x128 tile, global_load_lds w=16,
// XOR-swizzled LDS), fp32 state + epilogue-fused Heun combine.

#define BATCHN 8192
#define DDIM 512
#define HDIM 2048

typedef short short8 __attribute__((ext_vector_type(8)));
typedef float floatx4 __attribute__((ext_vector_type(4)));

__device__ __forceinline__ unsigned short f2bf(float f) {
  union { __hip_bfloat16 h; unsigned short u; } cv;
  cv.h = __float2bfloat16(f);
  return cv.u;
}

__device__ __forceinline__ float fast_tanh(float x) {
  // tanh(x) = 1 - 2/(e^{2x}+1); exact identity, __expf ~1e-7 rel err.
  // Saturates correctly: x>>0 -> e=inf -> 1; x<<0 -> e=0 -> -1.
  float e = __expf(2.0f * x);
  return 1.0f - 2.0f / (e + 1.0f);
}

__device__ __forceinline__ void load16_lds(const void* g, void* l) {
  // as3 pointers are 32-bit LDS offsets; low 32 bits of the flat shared
  // address are the offset (4GB-aligned aperture on gfx9+).
  __builtin_amdgcn_global_load_lds(
      (const __attribute__((address_space(1))) void*)(uintptr_t)g,
      (__attribute__((address_space(3))) void*)(uint32_t)(uintptr_t)l,
      16, 0, 0);
}

// C[M,N] = A[M,K] @ BT[N,K]^T, A/BT bf16 row-major, epilogue fused.
// EPI 0: out_bf = bf16(tanh(acc + bias))                      (h = tanh(y@W1+b1))
// EPI 1: k1 = acc+bias; ymid = y + dt*k1; store ymid f32+bf16
// EPI 2: k2 = acc+bias; ynew = 0.5*(y+ymid) + 0.5*dt*k2; store ynew f32+bf16
template <int K, int NN, int EPI>
__global__ __launch_bounds__(256, 3) void gemm_bt(
    const unsigned short* __restrict__ A,   // [M][K] bf16 bits
    const unsigned short* __restrict__ BT,  // [NN][K] bf16 bits
    const float* __restrict__ bias,         // [NN]
    unsigned short* bfOut,                  // [M][NN]
    const float* yIn,                       // EPI 1,2 (may alias fOut in EPI2)
    const float* ymidIn,                    // EPI 2
    float* fOut) {                          // EPI 1,2
  __shared__ unsigned short sA[128 * 64];
  __shared__ unsigned short sB[128 * 64];

  const int tid  = threadIdx.x;
  const int lane = tid & 63;
  const int wave = tid >> 6;
  const int wr   = wave >> 1;   // 2x2 wave grid, each wave 64x64
  const int wc   = wave & 1;
  const int quad = lane >> 4;
  const int l15  = lane & 15;

  const int bm = blockIdx.y * 128;
  const int bn = blockIdx.x * 128;

  // Staging: tile row = 128B = 8 chunks of 16B. LDS slot (row, schunk) holds
  // global chunk schunk ^ (row&7)  -> fragment ds_read_b128 is 2-way aliased
  // (free) instead of 16-way. global_load_lds dest = wave base + lane*16. [m104]
  const int srow   = tid >> 3;   // 0..31
  const int schunk = tid & 7;
  const int gchunk = schunk ^ (srow & 7);

  const unsigned short* Ag = A  + (size_t)(bm + srow) * K + gchunk * 8;
  const unsigned short* Bg = BT + (size_t)(bn + srow) * K + gchunk * 8;
  unsigned short* Al = &sA[srow * 64 + schunk * 8];
  unsigned short* Bl = &sB[srow * 64 + schunk * 8];

  floatx4 acc[4][4] = {};

  for (int kt = 0; kt < K; kt += 64) {
#pragma unroll
    for (int rd = 0; rd < 4; ++rd) {
      load16_lds(Ag + (size_t)(rd * 32) * K + kt, Al + rd * 32 * 64);
      load16_lds(Bg + (size_t)(rd * 32) * K + kt, Bl + rd * 32 * 64);
    }
    __syncthreads();
#pragma unroll
    for (int kk = 0; kk < 2; ++kk) {
      short8 av[4], bv[4];
      const int cbase = (kk * 4 + quad) ^ (l15 & 7);  // row&7 == l15&7 here
#pragma unroll
      for (int i = 0; i < 4; ++i) {
        av[i] = *(const short8*)(sA + (wr * 64 + i * 16 + l15) * 64 + cbase * 8);
        bv[i] = *(const short8*)(sB + (wc * 64 + i * 16 + l15) * 64 + cbase * 8);
      }
#pragma unroll
      for (int mi = 0; mi < 4; ++mi)
#pragma unroll
        for (int ni = 0; ni < 4; ++ni)
          acc[mi][ni] = __builtin_amdgcn_mfma_f32_16x16x32_bf16(
              av[mi], bv[ni], acc[mi][ni], 0, 0, 0);
    }
    __syncthreads();
  }

  // Epilogue. C/D layout: row = quad*4 + r, col = l15 (verified m89/m91).
  const int row0 = bm + wr * 64 + quad * 4;
  const int col0 = bn + wc * 64 + l15;
#pragma unroll
  for (int mi = 0; mi < 4; ++mi) {
#pragma unroll
    for (int ni = 0; ni < 4; ++ni) {
      const int col = col0 + ni * 16;
      const float bcol = bias[col];
#pragma unroll
      for (int r = 0; r < 4; ++r) {
        const int row = row0 + mi * 16 + r;
        const size_t idx = (size_t)row * NN + col;
        const float v = acc[mi][ni][r] + bcol;
        if constexpr (EPI == 0) {
          bfOut[idx] = f2bf(fast_tanh(v));
        } else if constexpr (EPI == 1) {
          const float ym = yIn[idx] + 0.1f * v;
          fOut[idx] = ym;
          bfOut[idx] = f2bf(ym);
        } else {
          const float yn = 0.5f * (yIn[idx] + ymidIn[idx]) + 0.05f * v;
          fOut[idx] = yn;
          bfOut[idx] = f2bf(yn);
        }
      }
    }
  }
}

// out[c][r] = bf16(in[r][c]); in is [R][C] fp32. Grid (C/32, R/32), block (32,8).
__global__ void transpose_cast(const float* __restrict__ in,
                               unsigned short* __restrict__ out, int R, int C) {
  __shared__ float t[32][33];
  const int x  = blockIdx.x * 32 + threadIdx.x;
  const int y0 = blockIdx.y * 32;
#pragma unroll
  for (int j = threadIdx.y; j < 32; j += 8)
    t[j][threadIdx.x] = in[(size_t)(y0 + j) * C + x];
  __syncthreads();
  const int ox = y0 + threadIdx.x;           // out col = in row
  const int oy = blockIdx.x * 32;            // out row = in col
#pragma unroll
  for (int j = threadIdx.y; j < 32; j += 8)
    out[(size_t)(oy + j) * R + ox] = f2bf(t[threadIdx.x][j]);
}

__global__ void init_y(const float* __restrict__ y0, float* __restrict__ yF,
                       unsigned short* __restrict__ yBf, int n) {
  const int i = blockIdx.x * blockDim.x + threadIdx.x;
  if (i < n) {
    const float v = y0[i];
    yF[i] = v;
    yBf[i] = f2bf(v);
  }
}

extern "C" void kernel_launch(void* const* d_in, const int* in_sizes, int n_in,
                              void* d_out, int out_size, void* d_ws, size_t ws_size,
                              hipStream_t stream) {
  const float* y0 = (const float*)d_in[0];
  const float* W1 = (const float*)d_in[1];  // [512][2048]
  const float* b1 = (const float*)d_in[2];  // [2048]
  const float* W2 = (const float*)d_in[3];  // [2048][512]
  const float* b2 = (const float*)d_in[4];  // [512]

  char* ws = (char*)d_ws;
  float*          yF     = (float*)(ws);                        // 16 MB
  float*          ymidF  = (float*)(ws + (size_t)(16u << 20));  // 16 MB
  unsigned short* yBf    = (unsigned short*)(ws + (size_t)(32u << 20)); // 8 MB
  unsigned short* ymidBf = (unsigned short*)(ws + (size_t)(40u << 20)); // 8 MB
  unsigned short* hBf    = (unsigned short*)(ws + (size_t)(48u << 20)); // 32 MB
  unsigned short* w1t    = (unsigned short*)(ws + (size_t)(80u << 20)); // 2 MB
  unsigned short* w2t    = (unsigned short*)(ws + (size_t)(82u << 20)); // 2 MB

  // W1 [512][2048] -> w1t [2048][512]; W2 [2048][512] -> w2t [512][2048]
  transpose_cast<<<dim3(HDIM / 32, DDIM / 32), dim3(32, 8), 0, stream>>>(W1, w1t, DDIM, HDIM);
  transpose_cast<<<dim3(DDIM / 32, HDIM / 32), dim3(32, 8), 0, stream>>>(W2, w2t, HDIM, DDIM);
  init_y<<<(BATCHN * DDIM) / 256, 256, 0, stream>>>(y0, yF, yBf, BATCHN * DDIM);

  const dim3 g1(HDIM / 128, BATCHN / 128);  // (16, 64)
  const dim3 g2(DDIM / 128, BATCHN / 128);  // (4, 64)
  const dim3 blk(256);

  for (int s = 0; s < 10; ++s) {
    // k1 path: h = tanh(y@W1+b1); ymid = y + dt*(h@W2+b2)
    gemm_bt<DDIM, HDIM, 0><<<g1, blk, 0, stream>>>(yBf, w1t, b1, hBf, nullptr, nullptr, nullptr);
    gemm_bt<HDIM, DDIM, 1><<<g2, blk, 0, stream>>>(hBf, w2t, b2, ymidBf, yF, nullptr, ymidF);
    // k2 path: h = tanh(ymid@W1+b1); ynew = 0.5*(y+ymid) + 0.5*dt*(h@W2+b2)
    gemm_bt<DDIM, HDIM, 0><<<g1, blk, 0, stream>>>(ymidBf, w1t, b1, hBf, nullptr, nullptr, nullptr);
    float* yOut = (s == 9) ? (float*)d_out : yF;
    gemm_bt<HDIM, DDIM, 2><<<g2, blk, 0, stream>>>(hBf, w2t, b2, yBf, yF, ymidF, yOut);
  }
}

// Round 2
// 1419.512 us; speedup vs baseline: 1.1302x; 1.1302x over previous
//
#include <hip/hip_runtime.h>
#include <hip/hip_bf16.h>
#include <cstdint>

// Neural ODE: 10 Heun steps of f(y) = tanh(y@W1 + b1)@W2 + b2
// BATCH=8192, D=512, H=2048, dt=0.1
// R2: GEMM2 retiled 64x128 (512 blocks = 2 blocks/CU; was 256 = 1/CU,
// barrier-drain bound at 9.7% occupancy). EPI1 now stores p = y + 0.05*k1
// so EPI2 reads one fp32 array instead of two (-16 MB/step HBM).

#define BATCHN 8192
#define DDIM 512
#define HDIM 2048

typedef short short8 __attribute__((ext_vector_type(8)));
typedef float floatx4 __attribute__((ext_vector_type(4)));

__device__ __forceinline__ unsigned short f2bf(float f) {
  union { __hip_bfloat16 h; unsigned short u; } cv;
  cv.h = __float2bfloat16(f);
  return cv.u;
}

__device__ __forceinline__ float fast_tanh(float x) {
  float e = __expf(2.0f * x);
  return 1.0f - 2.0f / (e + 1.0f);
}

__device__ __forceinline__ void load16_lds(const void* g, void* l) {
  __builtin_amdgcn_global_load_lds(
      (const __attribute__((address_space(1))) void*)(uintptr_t)g,
      (__attribute__((address_space(3))) void*)(uint32_t)(uintptr_t)l,
      16, 0, 0);
}

// C[M,N] = A[M,K] @ BT[N,K]^T, A/BT bf16 row-major, epilogue fused.
// Tile BM x BN, 256 threads (2x2 waves, wave tile BM/2 x BN/2).
// EPI 0: out_bf = bf16(tanh(acc + bias))
// EPI 1: k1 = acc+bias; store bf16(y + dt*k1) and fp32 p = y + 0.05*k1
// EPI 2: k2 = acc+bias; ynew = p + 0.05*k2; store ynew f32+bf16
template <int K, int NN, int EPI, int BM, int BN>
__global__ __launch_bounds__(256, 3) void gemm_bt(
    const unsigned short* __restrict__ A,   // [M][K] bf16 bits
    const unsigned short* __restrict__ BT,  // [NN][K] bf16 bits
    const float* __restrict__ bias,         // [NN]
    unsigned short* bfOut,                  // [M][NN]
    const float* yIn,                       // EPI 1: y;  EPI 2: p
    float* fOut) {                          // EPI 1: p;  EPI 2: ynew
  constexpr int MI = BM / 32;  // acc frags per wave (m)
  constexpr int NI = BN / 32;  // acc frags per wave (n)
  __shared__ unsigned short sA[BM * 64];
  __shared__ unsigned short sB[BN * 64];

  const int tid  = threadIdx.x;
  const int lane = tid & 63;
  const int wave = tid >> 6;
  const int wr   = wave >> 1;   // 2x2 wave grid
  const int wc   = wave & 1;
  const int quad = lane >> 4;
  const int l15  = lane & 15;

  const int bm = blockIdx.y * BM;
  const int bn = blockIdx.x * BN;

  // Staging: tile row = 128B = 8 chunks of 16B. LDS slot (row, schunk) holds
  // global chunk schunk ^ (row&7) -> fragment ds_read_b128 is 2-way aliased
  // (free, m136). global_load_lds dest = wave base + lane*16. [m104]
  const int srow   = tid >> 3;   // 0..31
  const int schunk = tid & 7;
  const int gchunk = schunk ^ (srow & 7);

  const unsigned short* Ag = A  + (size_t)(bm + srow) * K + gchunk * 8;
  const unsigned short* Bg = BT + (size_t)(bn + srow) * K + gchunk * 8;
  unsigned short* Al = &sA[srow * 64 + schunk * 8];
  unsigned short* Bl = &sB[srow * 64 + schunk * 8];

  floatx4 acc[MI][NI] = {};

  for (int kt = 0; kt < K; kt += 64) {
#pragma unroll
    for (int rd = 0; rd < BM / 32; ++rd)
      load16_lds(Ag + (size_t)(rd * 32) * K + kt, Al + rd * 32 * 64);
#pragma unroll
    for (int rd = 0; rd < BN / 32; ++rd)
      load16_lds(Bg + (size_t)(rd * 32) * K + kt, Bl + rd * 32 * 64);
    __syncthreads();
#pragma unroll
    for (int kk = 0; kk < 2; ++kk) {
      short8 av[MI], bv[NI];
      const int cbase = (kk * 4 + quad) ^ (l15 & 7);  // (row&7) == (l15&7): bases are mult of 8
#pragma unroll
      for (int i = 0; i < MI; ++i)
        av[i] = *(const short8*)(sA + (wr * (BM / 2) + i * 16 + l15) * 64 + cbase * 8);
#pragma unroll
      for (int i = 0; i < NI; ++i)
        bv[i] = *(const short8*)(sB + (wc * (BN / 2) + i * 16 + l15) * 64 + cbase * 8);
#pragma unroll
      for (int mi = 0; mi < MI; ++mi)
#pragma unroll
        for (int ni = 0; ni < NI; ++ni)
          acc[mi][ni] = __builtin_amdgcn_mfma_f32_16x16x32_bf16(
              av[mi], bv[ni], acc[mi][ni], 0, 0, 0);
    }
    __syncthreads();
  }

  // Epilogue. C/D layout: row = quad*4 + r, col = l15 (verified m89/m91).
  const int row0 = bm + wr * (BM / 2) + quad * 4;
  const int col0 = bn + wc * (BN / 2) + l15;
#pragma unroll
  for (int mi = 0; mi < MI; ++mi) {
#pragma unroll
    for (int ni = 0; ni < NI; ++ni) {
      const int col = col0 + ni * 16;
      const float bcol = bias[col];
#pragma unroll
      for (int r = 0; r < 4; ++r) {
        const int row = row0 + mi * 16 + r;
        const size_t idx = (size_t)row * NN + col;
        const float v = acc[mi][ni][r] + bcol;
        if constexpr (EPI == 0) {
          bfOut[idx] = f2bf(fast_tanh(v));
        } else if constexpr (EPI == 1) {
          const float y = yIn[idx];
          fOut[idx] = y + 0.05f * v;          // p = y + (dt/2)*k1
          bfOut[idx] = f2bf(y + 0.1f * v);    // ymid (bf16, feeds next GEMM)
        } else {
          const float yn = yIn[idx] + 0.05f * v;  // ynew = p + (dt/2)*k2
          fOut[idx] = yn;
          bfOut[idx] = f2bf(yn);
        }
      }
    }
  }
}

// out[c][r] = bf16(in[r][c]); in is [R][C] fp32. Grid (C/32, R/32), block (32,8).
__global__ void transpose_cast(const float* __restrict__ in,
                               unsigned short* __restrict__ out, int R, int C) {
  __shared__ float t[32][33];
  const int x  = blockIdx.x * 32 + threadIdx.x;
  const int y0 = blockIdx.y * 32;
#pragma unroll
  for (int j = threadIdx.y; j < 32; j += 8)
    t[j][threadIdx.x] = in[(size_t)(y0 + j) * C + x];
  __syncthreads();
  const int ox = y0 + threadIdx.x;           // out col = in row
  const int oy = blockIdx.x * 32;            // out row = in col
#pragma unroll
  for (int j = threadIdx.y; j < 32; j += 8)
    out[(size_t)(oy + j) * R + ox] = f2bf(t[threadIdx.x][j]);
}

__global__ void init_y(const float* __restrict__ y0, float* __restrict__ yF,
                       unsigned short* __restrict__ yBf, int n) {
  const int i = blockIdx.x * blockDim.x + threadIdx.x;
  if (i < n) {
    const float v = y0[i];
    yF[i] = v;
    yBf[i] = f2bf(v);
  }
}

extern "C" void kernel_launch(void* const* d_in, const int* in_sizes, int n_in,
                              void* d_out, int out_size, void* d_ws, size_t ws_size,
                              hipStream_t stream) {
  const float* y0 = (const float*)d_in[0];
  const float* W1 = (const float*)d_in[1];  // [512][2048]
  const float* b1 = (const float*)d_in[2];  // [2048]
  const float* W2 = (const float*)d_in[3];  // [2048][512]
  const float* b2 = (const float*)d_in[4];  // [512]

  char* ws = (char*)d_ws;
  float*          yF     = (float*)(ws);                        // 16 MB
  float*          pF     = (float*)(ws + (size_t)(16u << 20));  // 16 MB
  unsigned short* yBf    = (unsigned short*)(ws + (size_t)(32u << 20)); // 8 MB
  unsigned short* ymidBf = (unsigned short*)(ws + (size_t)(40u << 20)); // 8 MB
  unsigned short* hBf    = (unsigned short*)(ws + (size_t)(48u << 20)); // 32 MB
  unsigned short* w1t    = (unsigned short*)(ws + (size_t)(80u << 20)); // 2 MB
  unsigned short* w2t    = (unsigned short*)(ws + (size_t)(82u << 20)); // 2 MB

  // W1 [512][2048] -> w1t [2048][512]; W2 [2048][512] -> w2t [512][2048]
  transpose_cast<<<dim3(HDIM / 32, DDIM / 32), dim3(32, 8), 0, stream>>>(W1, w1t, DDIM, HDIM);
  transpose_cast<<<dim3(DDIM / 32, HDIM / 32), dim3(32, 8), 0, stream>>>(W2, w2t, HDIM, DDIM);
  init_y<<<(BATCHN * DDIM) / 256, 256, 0, stream>>>(y0, yF, yBf, BATCHN * DDIM);

  const dim3 g1(HDIM / 128, BATCHN / 128);  // (16, 64)  = 1024 blocks
  const dim3 g2(DDIM / 128, BATCHN / 64);   // (4, 128)  = 512 blocks
  const dim3 blk(256);

  for (int s = 0; s < 10; ++s) {
    // k1 path: h = tanh(y@W1+b1); ymid = y + dt*k1; p = y + 0.05*k1
    gemm_bt<DDIM, HDIM, 0, 128, 128><<<g1, blk, 0, stream>>>(yBf, w1t, b1, hBf, nullptr, nullptr);
    gemm_bt<HDIM, DDIM, 1, 64, 128><<<g2, blk, 0, stream>>>(hBf, w2t, b2, ymidBf, yF, pF);
    // k2 path: h = tanh(ymid@W1+b1); ynew = p + 0.05*k2
    gemm_bt<DDIM, HDIM, 0, 128, 128><<<g1, blk, 0, stream>>>(ymidBf, w1t, b1, hBf, nullptr, nullptr);
    float* yOut = (s == 9) ? (float*)d_out : yF;
    gemm_bt<HDIM, DDIM, 2, 64, 128><<<g2, blk, 0, stream>>>(hBf, w2t, b2, yBf, pF, yOut);
  }
}

// Round 3
// 1403.513 us; speedup vs baseline: 1.1430x; 1.0114x over previous
//
#include <hip/hip_runtime.h>
#include <hip/hip_bf16.h>
#include <cstdint>

// Neural ODE: 10 Heun steps of f(y) = tanh(y@W1 + b1)@W2 + b2
// BATCH=8192, D=512, H=2048, dt=0.1
// R3: GEMM2 BK 64->128 (48KB LDS, still >=2 blocks/CU resident; halves
// barrier count, 32 MFMA/wave per barrier-pair). GEMM1 frozen at 128x128/BK64.

#define BATCHN 8192
#define DDIM 512
#define HDIM 2048

typedef short short8 __attribute__((ext_vector_type(8)));
typedef float floatx4 __attribute__((ext_vector_type(4)));

__device__ __forceinline__ unsigned short f2bf(float f) {
  union { __hip_bfloat16 h; unsigned short u; } cv;
  cv.h = __float2bfloat16(f);
  return cv.u;
}

__device__ __forceinline__ float fast_tanh(float x) {
  float e = __expf(2.0f * x);
  return 1.0f - 2.0f / (e + 1.0f);
}

__device__ __forceinline__ void load16_lds(const void* g, void* l) {
  __builtin_amdgcn_global_load_lds(
      (const __attribute__((address_space(1))) void*)(uintptr_t)g,
      (__attribute__((address_space(3))) void*)(uint32_t)(uintptr_t)l,
      16, 0, 0);
}

// C[M,N] = A[M,K] @ BT[N,K]^T, A/BT bf16 row-major, epilogue fused.
// Tile BM x BN x BK, 256 threads (2x2 waves, wave tile BM/2 x BN/2).
// EPI 0: out_bf = bf16(tanh(acc + bias))
// EPI 1: k1 = acc+bias; store bf16(y + dt*k1) and fp32 p = y + 0.05*k1
// EPI 2: k2 = acc+bias; ynew = p + 0.05*k2; store ynew f32+bf16
template <int K, int NN, int EPI, int BM, int BN, int BK>
__global__ __launch_bounds__(256, 3) void gemm_bt(
    const unsigned short* __restrict__ A,   // [M][K] bf16 bits
    const unsigned short* __restrict__ BT,  // [NN][K] bf16 bits
    const float* __restrict__ bias,         // [NN]
    unsigned short* bfOut,                  // [M][NN]
    const float* yIn,                       // EPI 1: y;  EPI 2: p
    float* fOut) {                          // EPI 1: p;  EPI 2: ynew
  constexpr int MI = BM / 32;        // acc frags per wave (m)
  constexpr int NI = BN / 32;        // acc frags per wave (n)
  constexpr int CHUNKS = BK / 8;     // 16B chunks per LDS row
  constexpr int RPP = 256 / CHUNKS;  // rows staged per pass
  __shared__ unsigned short sA[BM * BK];
  __shared__ unsigned short sB[BN * BK];

  const int tid  = threadIdx.x;
  const int lane = tid & 63;
  const int wave = tid >> 6;
  const int wr   = wave >> 1;   // 2x2 wave grid
  const int wc   = wave & 1;
  const int quad = lane >> 4;
  const int l15  = lane & 15;

  const int bm = blockIdx.y * BM;
  const int bn = blockIdx.x * BN;

  // Staging: LDS row = BK bf16 = CHUNKS x 16B. Slot (row, schunk) holds global
  // chunk schunk ^ (row & (CHUNKS-1)) -> fragment ds_read_b128 lands 8 lanes
  // per 4-bank group (conflict-free pattern, measured 0). Dest offset = 16*tid
  // (wave-uniform base + lane*16, required by global_load_lds [m104]).
  const int srow   = tid / CHUNKS;          // 0..RPP-1
  const int schunk = tid % CHUNKS;
  const int gchunk = schunk ^ (srow & (CHUNKS - 1));

  const unsigned short* Ag = A  + (size_t)(bm + srow) * K + gchunk * 8;
  const unsigned short* Bg = BT + (size_t)(bn + srow) * K + gchunk * 8;
  unsigned short* Al = &sA[srow * BK + schunk * 8];
  unsigned short* Bl = &sB[srow * BK + schunk * 8];

  floatx4 acc[MI][NI] = {};

  for (int kt = 0; kt < K; kt += BK) {
#pragma unroll
    for (int rd = 0; rd < BM / RPP; ++rd)
      load16_lds(Ag + (size_t)(rd * RPP) * K + kt, Al + rd * RPP * BK);
#pragma unroll
    for (int rd = 0; rd < BN / RPP; ++rd)
      load16_lds(Bg + (size_t)(rd * RPP) * K + kt, Bl + rd * RPP * BK);
    __syncthreads();
#pragma unroll
    for (int kk = 0; kk < BK / 32; ++kk) {
      short8 av[MI], bv[NI];
      // fragment row & (CHUNKS-1) == l15 & (CHUNKS-1): row bases are mult of 16
      const int cbase = (kk * 4 + quad) ^ (l15 & (CHUNKS - 1));
#pragma unroll
      for (int i = 0; i < MI; ++i)
        av[i] = *(const short8*)(sA + (wr * (BM / 2) + i * 16 + l15) * BK + cbase * 8);
#pragma unroll
      for (int i = 0; i < NI; ++i)
        bv[i] = *(const short8*)(sB + (wc * (BN / 2) + i * 16 + l15) * BK + cbase * 8);
#pragma unroll
      for (int mi = 0; mi < MI; ++mi)
#pragma unroll
        for (int ni = 0; ni < NI; ++ni)
          acc[mi][ni] = __builtin_amdgcn_mfma_f32_16x16x32_bf16(
              av[mi], bv[ni], acc[mi][ni], 0, 0, 0);
    }
    __syncthreads();
  }

  // Epilogue. C/D layout: row = quad*4 + r, col = l15 (verified m89/m91).
  const int row0 = bm + wr * (BM / 2) + quad * 4;
  const int col0 = bn + wc * (BN / 2) + l15;
#pragma unroll
  for (int mi = 0; mi < MI; ++mi) {
#pragma unroll
    for (int ni = 0; ni < NI; ++ni) {
      const int col = col0 + ni * 16;
      const float bcol = bias[col];
#pragma unroll
      for (int r = 0; r < 4; ++r) {
        const int row = row0 + mi * 16 + r;
        const size_t idx = (size_t)row * NN + col;
        const float v = acc[mi][ni][r] + bcol;
        if constexpr (EPI == 0) {
          bfOut[idx] = f2bf(fast_tanh(v));
        } else if constexpr (EPI == 1) {
          const float y = yIn[idx];
          fOut[idx] = y + 0.05f * v;          // p = y + (dt/2)*k1
          bfOut[idx] = f2bf(y + 0.1f * v);    // ymid (bf16, feeds next GEMM)
        } else {
          const float yn = yIn[idx] + 0.05f * v;  // ynew = p + (dt/2)*k2
          fOut[idx] = yn;
          bfOut[idx] = f2bf(yn);
        }
      }
    }
  }
}

// out[c][r] = bf16(in[r][c]); in is [R][C] fp32. Grid (C/32, R/32), block (32,8).
__global__ void transpose_cast(const float* __restrict__ in,
                               unsigned short* __restrict__ out, int R, int C) {
  __shared__ float t[32][33];
  const int x  = blockIdx.x * 32 + threadIdx.x;
  const int y0 = blockIdx.y * 32;
#pragma unroll
  for (int j = threadIdx.y; j < 32; j += 8)
    t[j][threadIdx.x] = in[(size_t)(y0 + j) * C + x];
  __syncthreads();
  const int ox = y0 + threadIdx.x;           // out col = in row
  const int oy = blockIdx.x * 32;            // out row = in col
#pragma unroll
  for (int j = threadIdx.y; j < 32; j += 8)
    out[(size_t)(oy + j) * R + ox] = f2bf(t[threadIdx.x][j]);
}

__global__ void init_y(const float* __restrict__ y0, float* __restrict__ yF,
                       unsigned short* __restrict__ yBf, int n) {
  const int i = blockIdx.x * blockDim.x + threadIdx.x;
  if (i < n) {
    const float v = y0[i];
    yF[i] = v;
    yBf[i] = f2bf(v);
  }
}

extern "C" void kernel_launch(void* const* d_in, const int* in_sizes, int n_in,
                              void* d_out, int out_size, void* d_ws, size_t ws_size,
                              hipStream_t stream) {
  const float* y0 = (const float*)d_in[0];
  const float* W1 = (const float*)d_in[1];  // [512][2048]
  const float* b1 = (const float*)d_in[2];  // [2048]
  const float* W2 = (const float*)d_in[3];  // [2048][512]
  const float* b2 = (const float*)d_in[4];  // [512]

  char* ws = (char*)d_ws;
  float*          yF     = (float*)(ws);                        // 16 MB
  float*          pF     = (float*)(ws + (size_t)(16u << 20));  // 16 MB
  unsigned short* yBf    = (unsigned short*)(ws + (size_t)(32u << 20)); // 8 MB
  unsigned short* ymidBf = (unsigned short*)(ws + (size_t)(40u << 20)); // 8 MB
  unsigned short* hBf    = (unsigned short*)(ws + (size_t)(48u << 20)); // 32 MB
  unsigned short* w1t    = (unsigned short*)(ws + (size_t)(80u << 20)); // 2 MB
  unsigned short* w2t    = (unsigned short*)(ws + (size_t)(82u << 20)); // 2 MB

  // W1 [512][2048] -> w1t [2048][512]; W2 [2048][512] -> w2t [512][2048]
  transpose_cast<<<dim3(HDIM / 32, DDIM / 32), dim3(32, 8), 0, stream>>>(W1, w1t, DDIM, HDIM);
  transpose_cast<<<dim3(DDIM / 32, HDIM / 32), dim3(32, 8), 0, stream>>>(W2, w2t, HDIM, DDIM);
  init_y<<<(BATCHN * DDIM) / 256, 256, 0, stream>>>(y0, yF, yBf, BATCHN * DDIM);

  const dim3 g1(HDIM / 128, BATCHN / 128);  // (16, 64)  = 1024 blocks
  const dim3 g2(DDIM / 128, BATCHN / 64);   // (4, 128)  = 512 blocks
  const dim3 blk(256);

  for (int s = 0; s < 10; ++s) {
    // k1 path: h = tanh(y@W1+b1); ymid = y + dt*k1; p = y + 0.05*k1
    gemm_bt<DDIM, HDIM, 0, 128, 128, 64><<<g1, blk, 0, stream>>>(yBf, w1t, b1, hBf, nullptr, nullptr);
    gemm_bt<HDIM, DDIM, 1, 64, 128, 128><<<g2, blk, 0, stream>>>(hBf, w2t, b2, ymidBf, yF, pF);
    // k2 path: h = tanh(ymid@W1+b1); ynew = p + 0.05*k2
    gemm_bt<DDIM, HDIM, 0, 128, 128, 64><<<g1, blk, 0, stream>>>(ymidBf, w1t, b1, hBf, nullptr, nullptr);
    float* yOut = (s == 9) ? (float*)d_out : yF;
    gemm_bt<HDIM, DDIM, 2, 64, 128, 128><<<g2, blk, 0, stream>>>(hBf, w2t, b2, yBf, pF, yOut);
  }
}

// Round 6
// 1229.003 us; speedup vs baseline: 1.3053x; 1.1420x over previous
//
#include <hip/hip_runtime.h>
#include <hip/hip_bf16.h>
#include <cstdint>

// Neural ODE: 10 Heun steps of f(y) = tanh(y@W1 + b1)@W2 + b2
// BATCH=8192, D=512, H=2048, dt=0.1
// R6 (= R4 design, compile-clean): fully-fused f-eval kernel. 256 blocks
// (1/CU) x 1024 threads (16 waves). Weights pre-packed in MFMA B-frag order
// -> coalesced 16B/lane global loads served by L2 (4 MB working set);
// h[32 x 2048] lives only in LDS (CW=256 chunks, double-buffered, 1 barrier
// per chunk). Eliminates the 64 MB/eval h round-trip and the two-serial-
// kernel structure of R1-R3.

#define BATCHN 8192
#define DDIM 512
#define HDIM 2048
#define CW 256          // chunk width over H
#define NCH (HDIM / CW) // 8

typedef short short8 __attribute__((ext_vector_type(8)));
typedef float floatx4 __attribute__((ext_vector_type(4)));

__device__ __forceinline__ unsigned short f2bf(float f) {
  union { __hip_bfloat16 h; unsigned short u; } cv;
  cv.h = __float2bfloat16(f);
  return cv.u;
}

__device__ __forceinline__ float fast_tanh(float x) {
  float e = __expf(2.0f * x);
  return 1.0f - 2.0f / (e + 1.0f);
}

__device__ __forceinline__ void glds16(const void* g, void* l) {
  __builtin_amdgcn_global_load_lds(
      (const __attribute__((address_space(1))) void*)(uintptr_t)g,
      (__attribute__((address_space(3))) void*)(uint32_t)(uintptr_t)l,
      16, 0, 0);
}

// Fragment conventions (verified by R1-R3 passing kernels):
//  A-frag (16x16x32): lane holds A[m = l15][k = quad*8 + j], j=0..7 (16B)
//  B-frag:            lane holds B[n = l15][k = quad*8 + j]  (BT row-major)
//  C/D:               row = quad*4 + r, col = l15
// Packed buffers: frag f stored at [(f*64 + lane)*8] halves.
//  yPack: f = rb*16 + ks   (rb = batch-row/16: 0..511, ks = D k-step: 0..15)
//  w1p:   f = nb*16 + kb   (nb = H col-tile: 0..127,   kb = D k-step: 0..15)
//  w2p:   f = nb*64 + kb   (nb = D col-tile: 0..31,    kb = H k-step: 0..63)

__global__ __launch_bounds__(1024, 4) void fused_feval(
    const unsigned short* __restrict__ yPack,   // packed bf16 eval input
    const unsigned short* __restrict__ w1p,
    const unsigned short* __restrict__ w2p,
    const float* __restrict__ b1,
    const float* __restrict__ b2,
    const float* __restrict__ stateIn,   // EPI1: y fp32 ; EPI2: p fp32
    float* __restrict__ stateOut,        // EPI1: p      ; EPI2: ynew
    unsigned short* __restrict__ outPack,// packed bf16 next-eval input
    int epi) {                           // 1 or 2
  __shared__ unsigned short yA[32 * 512];       // 32 KB, frag (mt*16+ks)
  __shared__ unsigned short hA[2][32 * CW];     // 2 x 16 KB, frag (mt*8+ks)

  const int tid  = threadIdx.x;
  const int lane = tid & 63;
  const int w    = tid >> 6;    // wave 0..15
  const int quad = lane >> 4;
  const int l15  = lane & 15;
  const int blk  = blockIdx.x;  // 0..255
  const int B0   = blk * 32;    // slab base row

  // phase0: linear copy of this block's 32 KB packed y-slab into LDS.
  {
    const unsigned short* src = yPack + (size_t)blk * (32 * 512);
    glds16(src + (size_t)tid * 8, &yA[tid * 8]);
    glds16(src + (size_t)(1024 + tid) * 8, &yA[(1024 + tid) * 8]);
  }
  __syncthreads();

  floatx4 accY[2][2] = {};  // ymid acc: (mt, i), cols w*32 + i*16 + l15

  for (int c = 0; c < NCH; ++c) {
    // ---- phase1: h[:, c*CW + w*16 .. +16] = tanh(y @ W1-slice + b1) ----
    floatx4 acc1[2] = {};
    const int nb1 = c * 16 + w;  // H col-tile 0..127
#pragma unroll
    for (int ks = 0; ks < 16; ++ks) {
      short8 a0 = *(const short8*)&yA[((0 * 16 + ks) * 64 + lane) * 8];
      short8 a1 = *(const short8*)&yA[((1 * 16 + ks) * 64 + lane) * 8];
      short8 b  = *(const short8*)&w1p[((size_t)(nb1 * 16 + ks) * 64 + lane) * 8];
      acc1[0] = __builtin_amdgcn_mfma_f32_16x16x32_bf16(a0, b, acc1[0], 0, 0, 0);
      acc1[1] = __builtin_amdgcn_mfma_f32_16x16x32_bf16(a1, b, acc1[1], 0, 0, 0);
    }
    // bias + tanh + scatter into hA[c&1] in A-frag layout (k = h-col in chunk)
    {
      unsigned short* hbuf = hA[c & 1];
      const int kloc = w * 16 + l15;        // 0..255 (this lane's h-col)
      const float bb = b1[c * CW + kloc];
      const int ksa = kloc >> 5;
      const int qa  = (kloc & 31) >> 3;
      const int kb7 = kloc & 7;
#pragma unroll
      for (int mt = 0; mt < 2; ++mt)
#pragma unroll
        for (int r = 0; r < 4; ++r) {
          const int m15 = quad * 4 + r;     // C row -> A-frag m
          hbuf[((mt * 8 + ksa) * 64 + qa * 16 + m15) * 8 + kb7] =
              f2bf(fast_tanh(acc1[mt][r] + bb));
        }
    }
    // ---- phase2 for chunk c-1: accY += h_prev @ W2-slice ----
    if (c > 0) {
      const unsigned short* hprev = hA[(c - 1) & 1];
      const int kb0 = (c - 1) * 8;
#pragma unroll
      for (int ks = 0; ks < 8; ++ks) {
        short8 a0 = *(const short8*)&hprev[((0 * 8 + ks) * 64 + lane) * 8];
        short8 a1 = *(const short8*)&hprev[((1 * 8 + ks) * 64 + lane) * 8];
#pragma unroll
        for (int i = 0; i < 2; ++i) {
          const int nb2 = w * 2 + i;        // D col-tile 0..31
          short8 b = *(const short8*)&w2p[((size_t)(nb2 * 64 + kb0 + ks) * 64 + lane) * 8];
          accY[0][i] = __builtin_amdgcn_mfma_f32_16x16x32_bf16(a0, b, accY[0][i], 0, 0, 0);
          accY[1][i] = __builtin_amdgcn_mfma_f32_16x16x32_bf16(a1, b, accY[1][i], 0, 0, 0);
        }
      }
    }
    __syncthreads();
  }
  // tail phase2: chunk NCH-1 (buffer (NCH-1)&1 = 1)
  {
    const unsigned short* hprev = hA[(NCH - 1) & 1];
    const int kb0 = (NCH - 1) * 8;
#pragma unroll
    for (int ks = 0; ks < 8; ++ks) {
      short8 a0 = *(const short8*)&hprev[((0 * 8 + ks) * 64 + lane) * 8];
      short8 a1 = *(const short8*)&hprev[((1 * 8 + ks) * 64 + lane) * 8];
#pragma unroll
      for (int i = 0; i < 2; ++i) {
        const int nb2 = w * 2 + i;
        short8 b = *(const short8*)&w2p[((size_t)(nb2 * 64 + kb0 + ks) * 64 + lane) * 8];
        accY[0][i] = __builtin_amdgcn_mfma_f32_16x16x32_bf16(a0, b, accY[0][i], 0, 0, 0);
        accY[1][i] = __builtin_amdgcn_mfma_f32_16x16x32_bf16(a1, b, accY[1][i], 0, 0, 0);
      }
    }
  }
  __syncthreads();  // all waves done reading hA before reuse as pack staging

  // Epilogue: add b2, Heun combine with fp32 state, pack bf16 result.
  {
    unsigned short* pbuf = &hA[0][0];  // 32 KB staging, yA layout (mt*16+ksa)
#pragma unroll
    for (int i = 0; i < 2; ++i) {
      const int ncol = w * 32 + i * 16 + l15;  // 0..511
      const float bb = b2[ncol];
      const int ksa = ncol >> 5;
      const int qa  = (ncol & 31) >> 3;
      const int nb7 = ncol & 7;
#pragma unroll
      for (int mt = 0; mt < 2; ++mt)
#pragma unroll
        for (int r = 0; r < 4; ++r) {
          const int row = B0 + mt * 16 + quad * 4 + r;
          const size_t idx = (size_t)row * DDIM + ncol;
          const float v = accY[mt][i][r] + bb;
          float nv;
          if (epi == 1) {
            const float y = stateIn[idx];
            stateOut[idx] = y + 0.05f * v;   // p = y + (dt/2)*k1
            nv = y + 0.1f * v;               // ymid
          } else {
            const float yn = stateIn[idx] + 0.05f * v;  // ynew = p + (dt/2)*k2
            stateOut[idx] = yn;
            nv = yn;
          }
          const int m15 = quad * 4 + r;
          pbuf[((mt * 16 + ksa) * 64 + qa * 16 + m15) * 8 + nb7] = f2bf(nv);
        }
    }
    __syncthreads();
    unsigned short* dst = outPack + (size_t)blk * (32 * 512);
#pragma unroll
    for (int p = 0; p < 2; ++p) {
      short8 v = *(const short8*)&pbuf[(size_t)(p * 1024 + tid) * 8];
      *(short8*)&dst[(size_t)(p * 1024 + tid) * 8] = v;
    }
  }
}

// Pack weight [K][N] fp32 -> B-frag order: frag f = nb*KB + kb,
// lane entry = src[kb*32 + quad*8 + j][nb*16 + l15].
__global__ void pack_b(const float* __restrict__ src, unsigned short* __restrict__ dst,
                       int KB, int N) {
  const int t = blockIdx.x * 256 + threadIdx.x;
  const int lane = t & 63, f = t >> 6;
  const int nb = f / KB, kb = f % KB;
  const int quad = lane >> 4, l15 = lane & 15;
  const int k0 = kb * 32 + quad * 8, n = nb * 16 + l15;
  short8 v;
#pragma unroll
  for (int j = 0; j < 8; ++j)
    v[j] = (short)f2bf(src[(size_t)(k0 + j) * N + n]);
  *(short8*)&dst[(size_t)t * 8] = v;
}

// y0 fp32 [8192][512] -> yF fp32 copy + packed bf16 A-frags.
__global__ void pack_y(const float* __restrict__ y0, float* __restrict__ yF,
                       unsigned short* __restrict__ ypk) {
  const int t = blockIdx.x * 256 + threadIdx.x;
  const int lane = t & 63, f = t >> 6;
  const int rb = f >> 4, ks = f & 15;
  const int quad = lane >> 4, l15 = lane & 15;
  const int row = rb * 16 + l15, c0 = ks * 32 + quad * 8;
  short8 v;
#pragma unroll
  for (int j = 0; j < 8; ++j) {
    const float x = y0[(size_t)row * DDIM + c0 + j];
    yF[(size_t)row * DDIM + c0 + j] = x;
    v[j] = (short)f2bf(x);
  }
  *(short8*)&ypk[(size_t)t * 8] = v;
}

extern "C" void kernel_launch(void* const* d_in, const int* in_sizes, int n_in,
                              void* d_out, int out_size, void* d_ws, size_t ws_size,
                              hipStream_t stream) {
  const float* y0 = (const float*)d_in[0];
  const float* W1 = (const float*)d_in[1];  // [512][2048]
  const float* b1 = (const float*)d_in[2];  // [2048]
  const float* W2 = (const float*)d_in[3];  // [2048][512]
  const float* b2 = (const float*)d_in[4];  // [512]

  char* ws = (char*)d_ws;
  float*          yF   = (float*)(ws);                         // 16 MB
  float*          pF   = (float*)(ws + (size_t)(16u << 20));   // 16 MB
  unsigned short* ypk  = (unsigned short*)(ws + (size_t)(32u << 20)); // 8 MB
  unsigned short* ympk = (unsigned short*)(ws + (size_t)(40u << 20)); // 8 MB
  unsigned short* w1p  = (unsigned short*)(ws + (size_t)(48u << 20)); // 2 MB
  unsigned short* w2p  = (unsigned short*)(ws + (size_t)(50u << 20)); // 2 MB

  // Pre-pass: pack weights (2048 frags each) and y0 (8192 frags).
  pack_b<<<512, 256, 0, stream>>>(W1, w1p, 16, HDIM);
  pack_b<<<512, 256, 0, stream>>>(W2, w2p, 64, DDIM);
  pack_y<<<2048, 256, 0, stream>>>(y0, yF, ypk);

  const dim3 grid(256), blkd(1024);
  for (int s = 0; s < 10; ++s) {
    // eval1: k1 = f(y); p = y + 0.05*k1; ymid = y + 0.1*k1 (packed)
    fused_feval<<<grid, blkd, 0, stream>>>(ypk, w1p, w2p, b1, b2, yF, pF, ympk, 1);
    // eval2: k2 = f(ymid); ynew = p + 0.05*k2 (fp32 + packed)
    float* yOut = (s == 9) ? (float*)d_out : yF;
    fused_feval<<<grid, blkd, 0, stream>>>(ympk, w1p, w2p, b1, b2, pF, yOut, ypk, 2);
  }
}